// Round 11
// baseline (114.070 us; speedup 1.0000x reference)
//
#include <hip/hip_runtime.h>

#define TPTS 100   // points per voxel (T)
#define CO   64    // output channels
#define KK   8     // k-NN
#define NW   8     // waves per block (512 threads)

// Distances: the 9-dim edge feature is an affine image of the raw point
// p=(x,y,z,w): |f_t - f_s|^2 = 3dx^2+3dy^2+2dz^2+dw^2 (valid rows); masked
// columns give e = |f_t|^2 (9-dim norm, s_xx).  The same affine structure
// collapses conv: <feat, W> = <p, Weff> + const_v -> LDS holds only q[100][4].
// Top-8 via packed keys: (as_uint(e) & ~0x7F) | s -- uint order == float
// order (e >= 0), ties break by lowest index.
// R11: D split across ALL 8 waves. Row = wv + 8*lr (interleaved); each row's
// candidate list split 8 ways (nv<=64; 4 ways if nv>64) across lane groups;
// per-lane sorted-8 lists merged via shfl_xor half-clean + bitonic cleaner.
// R10 post-mortem: during D only ceil(nv/32)<=4 of 8 waves issued ->
// VALUBusy 66%; occupancy is NOT LDS-limited (55% flat across 3 LDS sizes).
__device__ __forceinline__ unsigned umin_(unsigned a, unsigned b) { return a < b ? a : b; }
__device__ __forceinline__ unsigned umax_(unsigned a, unsigned b) { return a > b ? a : b; }
__device__ __forceinline__ _Float16 hmax_(_Float16 a, _Float16 b) { return a > b ? a : b; }

__device__ __forceinline__ unsigned med3u(unsigned a, unsigned b, unsigned c) {
    unsigned d;
    asm("v_med3_u32 %0, %1, %2, %3" : "=v"(d) : "v"(a), "v"(b), "v"(c));
    return d;
}

// insert key into sorted-ascending val[0..7]; med3 identity, depth 2.
// Inserting 0xFFFFFFFF is a no-op (val[k-1]<=val[k]<=SENT -> median=val[k]).
__device__ __forceinline__ void ins8(unsigned val[KK], unsigned key) {
    #pragma unroll
    for (int k = KK - 1; k >= 1; --k)
        val[k] = med3u(val[k - 1], val[k], key);
    val[0] = umin_(val[0], key);
}

// half-clean with shfl partner: val <- min(val[k], other[7-k]) (bitonic out;
// the 8 smallest of the union -- set-exact when both lists are sorted asc)
__device__ __forceinline__ void hclean(unsigned val[KK], int mask) {
    unsigned other[KK];
    #pragma unroll
    for (int k = 0; k < KK; ++k) other[k] = __shfl_xor(val[k], mask, 64);
    unsigned t[KK];
    #pragma unroll
    for (int k = 0; k < KK; ++k) t[k] = umin_(val[k], other[KK - 1 - k]);
    #pragma unroll
    for (int k = 0; k < KK; ++k) val[k] = t[k];
}

// bitonic-8 cleaner: sorts any bitonic sequence ascending (3 stages x 4 CE)
__device__ __forceinline__ void bsort8(unsigned v[KK]) {
    #pragma unroll
    for (int k = 0; k < 4; ++k) {          // stage 4
        unsigned lo = umin_(v[k], v[k + 4]), hi = umax_(v[k], v[k + 4]);
        v[k] = lo; v[k + 4] = hi;
    }
    {   // stage 2: (0,2),(1,3),(4,6),(5,7)
        unsigned lo, hi;
        lo = umin_(v[0], v[2]); hi = umax_(v[0], v[2]); v[0] = lo; v[2] = hi;
        lo = umin_(v[1], v[3]); hi = umax_(v[1], v[3]); v[1] = lo; v[3] = hi;
        lo = umin_(v[4], v[6]); hi = umax_(v[4], v[6]); v[4] = lo; v[6] = hi;
        lo = umin_(v[5], v[7]); hi = umax_(v[5], v[7]); v[5] = lo; v[7] = hi;
    }
    {   // stage 1: (0,1),(2,3),(4,5),(6,7)
        unsigned lo, hi;
        lo = umin_(v[0], v[1]); hi = umax_(v[0], v[1]); v[0] = lo; v[1] = hi;
        lo = umin_(v[2], v[3]); hi = umax_(v[2], v[3]); v[2] = lo; v[3] = hi;
        lo = umin_(v[4], v[5]); hi = umax_(v[4], v[5]); v[4] = lo; v[5] = hi;
        lo = umin_(v[6], v[7]); hi = umax_(v[6], v[7]); v[6] = lo; v[7] = hi;
    }
}

__global__ __launch_bounds__(512) void dgcnn_kernel(
    const float* __restrict__ features,   // [V][100][4]
    const float* __restrict__ conv_w,     // [64][18]
    const float* __restrict__ bn_gamma,
    const float* __restrict__ bn_beta,
    const float* __restrict__ bn_mean,
    const float* __restrict__ bn_var,
    const int*  __restrict__ num_voxels,  // [V]
    const int*  __restrict__ coors,       // [V][4]
    float* __restrict__ out)              // [V][64]
{
    __shared__ float    s_q[TPTS][4];      // 1600 B scaled coords (fp32, exact D)
    __shared__ float    s_xx[TPTS];        //  400 B 9-dim |feat|^2
    __shared__ unsigned s_idxp[TPTS][2];   //  800 B 8 neighbor idx, 8b each
    __shared__ float    s_mean[4];         //   16 B
    __shared__ union {                     // 12800 B (time-shared)
        float    stage[TPTS][4];           // raw features (A/B)
        _Float16 g16[TPTS][CO];            // g[s][o] fp16 (E/F)
        float    red[NW][CO];              // wave partials (post-F, barriered)
    } s_u;

    const float INF = __builtin_inff();
    const int v   = blockIdx.x;
    const int tid = threadIdx.x;
    const int nv  = num_voxels[v];

    // ---- Phase A: stage raw features ----
    float4 f = make_float4(0.f, 0.f, 0.f, 0.f);
    if (tid < TPTS) {
        f = reinterpret_cast<const float4*>(features)[v * TPTS + tid];
        *reinterpret_cast<float4*>(&s_u.stage[tid][0]) = f;
    }
    __syncthreads();

    // ---- Phase B: mean of ch 0..2 over ALL 100 raw rows, / nv ----
    if (tid < 96) {
        int ch = tid >> 5, j = tid & 31;
        float p = s_u.stage[j][ch] + s_u.stage[j + 32][ch] + s_u.stage[j + 64][ch];
        if (j < 4) p += s_u.stage[j + 96][ch];
        #pragma unroll
        for (int off = 16; off >= 1; off >>= 1)
            p += __shfl_xor(p, off, 32);
        if (j == 0) s_mean[ch] = p / (float)nv;
    }
    __syncthreads();

    // per-voxel center (uniform scalar loads)
    const float cx = (float)coors[v * 4 + 3] * 0.2f + 0.1f;    // VX, X_OFF
    const float cy = (float)coors[v * 4 + 2] * 0.2f - 39.9f;   // VY, Y_OFF
    const float m0 = s_mean[0], m1 = s_mean[1], m2 = s_mean[2];

    // ---- Phase C: masked scaled coords q + 9-dim norm xx ----
    if (tid < TPTS) {
        float mask = (tid < nv) ? 1.0f : 0.0f;
        float r0 = f.x * mask, r1 = f.y * mask, r2 = f.z * mask, r3 = f.w * mask;
        float r4 = (f.x - m0) * mask;
        float r5 = (f.y - m1) * mask;
        float r6 = (f.z - m2) * mask;
        float r7 = (f.x - cx) * mask;
        float r8 = (f.y - cy) * mask;
        float xx = r0*r0 + r1*r1 + r2*r2 + r3*r3 + r4*r4
                 + r5*r5 + r6*r6 + r7*r7 + r8*r8;
        *reinterpret_cast<float4*>(&s_q[tid][0]) =
            make_float4(1.7320508075688772f * r0,
                        1.7320508075688772f * r1,
                        1.4142135623730951f * r2, r3);
        s_xx[tid] = xx;
    }

    // ---- effective weights (affine collapse; applied to scaled q) ----
    const int o  = tid & 63;               // lane
    const int wv = tid >> 6;               // wave id 0..7
    const float sgn = (bn_gamma[o] < 0.f) ? -1.f : 1.f;
    float w1r[9], w2r[9];
    {   // vectorized: 9 float2 loads (o*18 floats = o*72B, 8-aligned)
        const float2* wrow = reinterpret_cast<const float2*>(conv_w + o * 18);
        float wa[18];
        #pragma unroll
        for (int c = 0; c < 9; ++c) {
            float2 p = wrow[c];
            wa[2 * c] = p.x; wa[2 * c + 1] = p.y;
        }
        #pragma unroll
        for (int c = 0; c < 9; ++c) {
            w1r[c] = wa[c] * sgn;
            w2r[c] = (wa[9 + c] - wa[c]) * sgn;
        }
    }
    const float i3 = 0.57735026918962576f, i2 = 0.70710678118654752f;
    float wq1[4], wq2[4];
    wq1[0] = (w1r[0] + w1r[4] + w1r[7]) * i3;
    wq1[1] = (w1r[1] + w1r[5] + w1r[8]) * i3;
    wq1[2] = (w1r[2] + w1r[6]) * i2;
    wq1[3] = w1r[3];
    wq2[0] = (w2r[0] + w2r[4] + w2r[7]) * i3;
    wq2[1] = (w2r[1] + w2r[5] + w2r[8]) * i3;
    wq2[2] = (w2r[2] + w2r[6]) * i2;
    wq2[3] = w2r[3];
    const float c1v = -(w1r[4]*m0 + w1r[5]*m1 + w1r[6]*m2 + w1r[7]*cx + w1r[8]*cy);
    const float c2v = -(w2r[4]*m0 + w2r[5]*m1 + w2r[6]*m2 + w2r[7]*cx + w2r[8]*cy);
    __syncthreads();

    // ---- zero-fill masked g rows [nv, min(nv+8,100)) — exact (+0.0) ----
    {
        int r0 = nv + wv;                  // 8 waves cover all 8 masked rows
        if (r0 < TPTS) s_u.g16[r0][o] = (_Float16)0.f;
    }

    // ---- Phase D: top-8 across ALL 8 waves.  Geometry: row = wv + 8*lr,
    //      candidate list [0, nv+mcnt) split across nseg lane groups;
    //      per-lane sorted-8 merged via shfl_xor half-clean (+ bitonic
    //      cleaner between rounds).  Selected SET bit-identical to a full
    //      serial scan (same packed keys). ----
    {
        const bool big = (nv > 64);        // block-uniform
        const int lr   = big ? (o & 15) : (o & 7);
        const int sg   = big ? (o >> 4) : (o >> 3);
        const int trow = wv + 8 * lr;      // interleaved rows
        const int tre  = (trow < nv) ? trow : (nv - 1);   // clamp: shfl-safe
        int mcnt = TPTS - nv; if (mcnt > KK) mcnt = KK;
        const int L  = nv + mcnt;          // unified candidate count
        const int LS = big ? 2 : 3;        // log2(nseg)
        const int q_ = L >> LS, r_ = L - (q_ << LS);
        const int len    = q_ + (sg < r_ ? 1 : 0);
        const int s0     = sg * q_ + (sg < r_ ? sg : r_);
        const int lenmax = q_ + (r_ ? 1 : 0);

        const float4 qt = *reinterpret_cast<const float4*>(&s_q[tre][0]);
        const unsigned kmb = __float_as_uint(s_xx[tre]) & 0xFFFFFF80u;
        unsigned val[KK];
        #pragma unroll
        for (int k = 0; k < KK; ++k) val[k] = 0xFFFFFFFFu;

        #pragma unroll 2
        for (int j = 0; j < lenmax; ++j) {
            int s  = s0 + j;
            int sc = (s < TPTS - 1) ? s : (TPTS - 1);    // clamp read addr
            const float4 qs = *reinterpret_cast<const float4*>(&s_q[sc][0]);
            float dx = qt.x - qs.x, dy = qt.y - qs.y;
            float dz = qt.z - qs.z, dw = qt.w - qs.w;
            float e = __fmaf_rn(dx, dx, __fmaf_rn(dy, dy,
                      __fmaf_rn(dz, dz, dw * dw)));
            unsigned hi = (s < nv) ? (__float_as_uint(e) & 0xFFFFFF80u) : kmb;
            unsigned key = hi | (unsigned)s;
            key = (j < len) ? key : 0xFFFFFFFFu;         // oob -> sentinel
            ins8(val, key);
        }

        if (big) {           // 4 segments: rounds xor16, xor32
            hclean(val, 16); bsort8(val);
            hclean(val, 32);
        } else {             // 8 segments: rounds xor8, xor16, xor32
            hclean(val, 8);  bsort8(val);
            hclean(val, 16); bsort8(val);
            hclean(val, 32);
        }
        if (sg == 0 && trow < nv) {        // publish set (order irrelevant)
            unsigned p0 =  (val[0] & 127u)        | ((val[1] & 127u) << 8)
                        | ((val[2] & 127u) << 16) | ((val[3] & 127u) << 24);
            unsigned p1 =  (val[4] & 127u)        | ((val[5] & 127u) << 8)
                        | ((val[6] & 127u) << 16) | ((val[7] & 127u) << 24);
            *reinterpret_cast<uint2*>(&s_idxp[trow][0]) = make_uint2(p0, p1);
        }
    }

    // ---- Phase E (all 8 waves, post-D): g = <q,wq1> + c1v, fp16 store ----
    for (int sR = wv; sR < nv; sR += NW) {
        const float4 q = *reinterpret_cast<const float4*>(&s_q[sR][0]);
        float g = c1v;
        g = __fmaf_rn(q.x, wq1[0], g);
        g = __fmaf_rn(q.y, wq1[1], g);
        g = __fmaf_rn(q.z, wq1[2], g);
        g = __fmaf_rn(q.w, wq1[3], g);
        s_u.g16[sR][o] = (_Float16)g;      // lane-consecutive 2B
    }
    __syncthreads();

    // ---- Phase F: acc[o] = max over valid t of (max_k g[idx]) + base[t] ----
    float acc = -INF;
    for (int tt = wv; tt < nv; tt += NW) { // interleaved across 8 waves
        const float4 q = *reinterpret_cast<const float4*>(&s_q[tt][0]);
        float base = c2v;
        base = __fmaf_rn(q.x, wq2[0], base);
        base = __fmaf_rn(q.y, wq2[1], base);
        base = __fmaf_rn(q.z, wq2[2], base);
        base = __fmaf_rn(q.w, wq2[3], base);
        uint2 pk = *reinterpret_cast<const uint2*>(&s_idxp[tt][0]);  // broadcast
        int i0 =  pk.x        & 255, i1 = (pk.x >>  8) & 255;
        int i2_ = (pk.x >> 16) & 255, i3_ = (pk.x >> 24) & 255;
        int i4 =  pk.y        & 255, i5 = (pk.y >>  8) & 255;
        int i6 = (pk.y >> 16) & 255, i7 = (pk.y >> 24) & 255;
        // 8-way max in fp16 (exact: max commutes with exact f16->f32 cvt)
        _Float16 g0 = s_u.g16[i0][o],  g1 = s_u.g16[i1][o];
        _Float16 g2 = s_u.g16[i2_][o], g3 = s_u.g16[i3_][o];
        _Float16 g4 = s_u.g16[i4][o],  g5 = s_u.g16[i5][o];
        _Float16 g6 = s_u.g16[i6][o],  g7 = s_u.g16[i7][o];
        _Float16 gm = hmax_(hmax_(hmax_(g0, g1), hmax_(g2, g3)),
                            hmax_(hmax_(g4, g5), hmax_(g6, g7)));
        acc = fmaxf(acc, (float)gm + base);   // base hoisted out of the k-max
    }
    __syncthreads();                       // g16 reads done -> reuse as red
    s_u.red[wv][o] = acc;
    __syncthreads();

    // ---- Phase G: cross-wave reduce, BN + leakyReLU + mask-max, store ----
    if (tid < CO) {
        float m = s_u.red[0][tid];
        #pragma unroll
        for (int i = 1; i < NW; ++i) m = fmaxf(m, s_u.red[i][tid]);
        float scale = bn_gamma[tid] / sqrtf(bn_var[tid] + 0.001f);
        float bias  = bn_beta[tid] - bn_mean[tid] * scale;
        float h = m * fabsf(scale) + bias;    // m tracks sgn*h_pre
        float a = (h > 0.f) ? h : 0.2f * h;   // leaky_relu
        if (nv < TPTS) a = fmaxf(a, 0.f);     // masked rows contribute 0
        out[v * CO + tid] = a;
    }
}

extern "C" void kernel_launch(void* const* d_in, const int* in_sizes, int n_in,
                              void* d_out, int out_size, void* d_ws, size_t ws_size,
                              hipStream_t stream) {
    const float* features = (const float*)d_in[0];
    const float* conv_w   = (const float*)d_in[1];
    const float* bn_gamma = (const float*)d_in[2];
    const float* bn_beta  = (const float*)d_in[3];
    const float* bn_mean  = (const float*)d_in[4];
    const float* bn_var   = (const float*)d_in[5];
    const int*   num_vox  = (const int*)d_in[6];
    const int*   coor     = (const int*)d_in[7];
    float* outp = (float*)d_out;
    const int V = in_sizes[6];   // 4096 voxels
    dgcnn_kernel<<<V, 512, 0, stream>>>(features, conv_w, bn_gamma, bn_beta,
                                        bn_mean, bn_var, num_vox, coor, outp);
}

// Round 12
// 105.935 us; speedup vs baseline: 1.0768x; 1.0768x over previous
//
#include <hip/hip_runtime.h>

#define TPTS 100   // points per voxel (T)
#define CO   64    // output channels
#define KK   8     // k-NN
#define NW   8     // waves per block (512 threads)

// Distances: the 9-dim edge feature is an affine image of the raw point
// p=(x,y,z,w): |f_t - f_s|^2 = 3dx^2+3dy^2+2dz^2+dw^2 (valid rows); masked
// columns give e = |f_t|^2 (9-dim norm, s_xx).  The same affine structure
// collapses conv: <feat, W> = <p, Weff> + const_v -> LDS holds only q[100][4].
// Top-8 via packed keys: (as_uint(e) & ~0x7F) | s -- uint order == float
// order (e >= 0), ties break by lowest index.
// R12: revert to R10 structure (R11's 8-way D split raised total issue and
// regressed).  Cut issue where it concentrates: Phase F processes TWO rows
// per wave-iteration with fp16 channel-PAIRS (v_pk_max_f16 for the 8-way
// neighbor max -- exact), fp32 epilogue -> bit-identical output to R10.
// Phase E same pairing.  Pair weights come from 20 one-time shfls.
__device__ __forceinline__ unsigned umin_(unsigned a, unsigned b) { return a < b ? a : b; }

__device__ __forceinline__ unsigned med3u(unsigned a, unsigned b, unsigned c) {
    unsigned d;
    asm("v_med3_u32 %0, %1, %2, %3" : "=v"(d) : "v"(a), "v"(b), "v"(c));
    return d;
}

__device__ __forceinline__ unsigned pkmaxh(unsigned a, unsigned b) {
    unsigned d;
    asm("v_pk_max_f16 %0, %1, %2" : "=v"(d) : "v"(a), "v"(b));
    return d;
}

// insert key into sorted-ascending val[0..7]; med3 identity, depth 2.
__device__ __forceinline__ void ins8(unsigned val[KK], unsigned key) {
    #pragma unroll
    for (int k = KK - 1; k >= 1; --k)
        val[k] = med3u(val[k - 1], val[k], key);
    val[0] = umin_(val[0], key);
}

__global__ __launch_bounds__(512) void dgcnn_kernel(
    const float* __restrict__ features,   // [V][100][4]
    const float* __restrict__ conv_w,     // [64][18]
    const float* __restrict__ bn_gamma,
    const float* __restrict__ bn_beta,
    const float* __restrict__ bn_mean,
    const float* __restrict__ bn_var,
    const int*  __restrict__ num_voxels,  // [V]
    const int*  __restrict__ coors,       // [V][4]
    float* __restrict__ out)              // [V][64]
{
    __shared__ float    s_q[TPTS][4];      // 1600 B scaled coords (fp32, exact D)
    __shared__ float    s_xx[TPTS];        //  400 B 9-dim |feat|^2
    __shared__ unsigned s_idxp[TPTS][2];   //  800 B 8 neighbor idx, 8b each
    __shared__ float    s_red[NW][CO];     // 2048 B
    __shared__ float    s_mean[4];         //   16 B
    __shared__ union {                     // 12800 B (time-shared)
        float    stage[TPTS][4];           // raw features (A/B)
        _Float16 g16[TPTS][CO];            // g[s][o] fp16 (E/F)
    } s_u;                                 // total ~17.7 KB

    const float INF = __builtin_inff();
    const int v   = blockIdx.x;
    const int tid = threadIdx.x;
    const int nv  = num_voxels[v];

    // ---- Phase A: stage raw features ----
    float4 f = make_float4(0.f, 0.f, 0.f, 0.f);
    if (tid < TPTS) {
        f = reinterpret_cast<const float4*>(features)[v * TPTS + tid];
        *reinterpret_cast<float4*>(&s_u.stage[tid][0]) = f;
    }
    __syncthreads();

    // ---- Phase B: mean of ch 0..2 over ALL 100 raw rows, / nv ----
    if (tid < 96) {
        int ch = tid >> 5, j = tid & 31;
        float p = s_u.stage[j][ch] + s_u.stage[j + 32][ch] + s_u.stage[j + 64][ch];
        if (j < 4) p += s_u.stage[j + 96][ch];
        #pragma unroll
        for (int off = 16; off >= 1; off >>= 1)
            p += __shfl_xor(p, off, 32);
        if (j == 0) s_mean[ch] = p / (float)nv;
    }
    __syncthreads();

    // per-voxel center (uniform scalar loads)
    const float cx = (float)coors[v * 4 + 3] * 0.2f + 0.1f;    // VX, X_OFF
    const float cy = (float)coors[v * 4 + 2] * 0.2f - 39.9f;   // VY, Y_OFF
    const float m0 = s_mean[0], m1 = s_mean[1], m2 = s_mean[2];

    // ---- Phase C: masked scaled coords q + 9-dim norm xx ----
    if (tid < TPTS) {
        float mask = (tid < nv) ? 1.0f : 0.0f;
        float r0 = f.x * mask, r1 = f.y * mask, r2 = f.z * mask, r3 = f.w * mask;
        float r4 = (f.x - m0) * mask;
        float r5 = (f.y - m1) * mask;
        float r6 = (f.z - m2) * mask;
        float r7 = (f.x - cx) * mask;
        float r8 = (f.y - cy) * mask;
        float xx = r0*r0 + r1*r1 + r2*r2 + r3*r3 + r4*r4
                 + r5*r5 + r6*r6 + r7*r7 + r8*r8;
        *reinterpret_cast<float4*>(&s_q[tid][0]) =
            make_float4(1.7320508075688772f * r0,
                        1.7320508075688772f * r1,
                        1.4142135623730951f * r2, r3);
        s_xx[tid] = xx;
    }

    // ---- effective weights (affine collapse; applied to scaled q) ----
    const int o   = tid & 63;              // lane
    const int wv  = tid >> 6;              // wave id 0..7
    const int o2  = o & 31;                // channel-pair id
    const int hlf = o >> 5;                // half-wave id
    const float sgn = (bn_gamma[o] < 0.f) ? -1.f : 1.f;
    float w1r[9], w2r[9];
    {   // vectorized: 9 float2 loads (o*18 floats = o*72B, 8-aligned)
        const float2* wrow = reinterpret_cast<const float2*>(conv_w + o * 18);
        float wa[18];
        #pragma unroll
        for (int c = 0; c < 9; ++c) {
            float2 p = wrow[c];
            wa[2 * c] = p.x; wa[2 * c + 1] = p.y;
        }
        #pragma unroll
        for (int c = 0; c < 9; ++c) {
            w1r[c] = wa[c] * sgn;
            w2r[c] = (wa[9 + c] - wa[c]) * sgn;
        }
    }
    const float i3 = 0.57735026918962576f, i2 = 0.70710678118654752f;
    float wq1[4], wq2[4];
    wq1[0] = (w1r[0] + w1r[4] + w1r[7]) * i3;
    wq1[1] = (w1r[1] + w1r[5] + w1r[8]) * i3;
    wq1[2] = (w1r[2] + w1r[6]) * i2;
    wq1[3] = w1r[3];
    wq2[0] = (w2r[0] + w2r[4] + w2r[7]) * i3;
    wq2[1] = (w2r[1] + w2r[5] + w2r[8]) * i3;
    wq2[2] = (w2r[2] + w2r[6]) * i2;
    wq2[3] = w2r[3];
    const float c1v = -(w1r[4]*m0 + w1r[5]*m1 + w1r[6]*m2 + w1r[7]*cx + w1r[8]*cy);
    const float c2v = -(w2r[4]*m0 + w2r[5]*m1 + w2r[6]*m2 + w2r[7]*cx + w2r[8]*cy);

    // pair weights: channel 2*o2 (A) and 2*o2+1 (B), pulled from owner lanes
    float wq1A[4], wq1B[4], wq2A[4], wq2B[4];
    #pragma unroll
    for (int c = 0; c < 4; ++c) {
        wq1A[c] = __shfl(wq1[c], 2 * o2);
        wq1B[c] = __shfl(wq1[c], 2 * o2 + 1);
        wq2A[c] = __shfl(wq2[c], 2 * o2);
        wq2B[c] = __shfl(wq2[c], 2 * o2 + 1);
    }
    const float c1A = __shfl(c1v, 2 * o2), c1B = __shfl(c1v, 2 * o2 + 1);
    const float c2A = __shfl(c2v, 2 * o2), c2B = __shfl(c2v, 2 * o2 + 1);
    __syncthreads();

    const int nd = (nv + 31) >> 5;         // # D-waves (1..4); >=4 waves free

    // ---- zero-fill masked g rows [nv, min(nv+8,100)) — exact (+0.0) ----
    {
        int r0 = nv + wv;                  // 8 waves cover all 8 masked rows
        if (r0 < TPTS) s_u.g16[r0][o] = (_Float16)0.f;
    }

    if (wv < nd) {
        // ---- Phase D: top-8, in-wave pair split (R10 geometry). Wave wv
        //      owns rows wv*32..+31; lanes 0-31 scan [0,ha), lanes 32-63
        //      scan [ha,nv)+masked; merge via shfl_xor 32. ----
        const int trow = wv * 32 + (o & 31);
        const int bsd  = o >> 5;           // 0 = A-half, 1 = B-half
        if (trow < nv) {
            const float4 qt = *reinterpret_cast<const float4*>(&s_q[trow][0]);
            unsigned val[KK];
            #pragma unroll
            for (int k = 0; k < KK; ++k) val[k] = 0xFFFFFFFFu;
            int mcnt = TPTS - nv; if (mcnt > KK) mcnt = KK;
            int ha = (nv + mcnt + 1) >> 1; if (ha > nv) ha = nv;  // balance
            int s        = bsd ? ha : 0;
            const int se = bsd ? nv : ha;
            #pragma unroll 2
            for (; s < se; ++s) {
                const float4 qs = *reinterpret_cast<const float4*>(&s_q[s][0]);
                float dx = qt.x - qs.x, dy = qt.y - qs.y;
                float dz = qt.z - qs.z, dw = qt.w - qs.w;
                float e = __fmaf_rn(dx, dx, __fmaf_rn(dy, dy,
                          __fmaf_rn(dz, dz, dw * dw)));
                ins8(val, (__float_as_uint(e) & 0xFFFFFF80u) | (unsigned)s);
            }
            if (bsd) {   // masked columns: e = |f_t|^2, idx nv, nv+1, ...
                unsigned kmb = __float_as_uint(s_xx[trow]) & 0xFFFFFF80u;
                for (int j = 0; j < mcnt; ++j)
                    ins8(val, kmb | (unsigned)(nv + j));
            }
            unsigned other[KK];            // pair partner's sorted list
            #pragma unroll
            for (int k = 0; k < KK; ++k) other[k] = __shfl_xor(val[k], 32);
            if (!bsd) {                    // A-half merges + publishes
                unsigned m[KK];
                #pragma unroll
                for (int k = 0; k < KK; ++k)   // 8 smallest of union (set-exact)
                    m[k] = umin_(val[k], other[KK - 1 - k]) & 127u;
                unsigned p0 = m[0] | (m[1] << 8) | (m[2] << 16) | (m[3] << 24);
                unsigned p1 = m[4] | (m[5] << 8) | (m[6] << 16) | (m[7] << 24);
                *reinterpret_cast<uint2*>(&s_idxp[trow][0]) = make_uint2(p0, p1);
            }
        }
    } else {
        // ---- Phase E (waves nd..7, concurrent with D): packed channel
        //      pair per lane, half-waves take adjacent rows. ----
        const int nE = NW - nd;
        for (int r = (wv - nd) * 2 + hlf; r < nv; r += 2 * nE) {
            const float4 q = *reinterpret_cast<const float4*>(&s_q[r][0]);
            float gA = c1A;
            gA = __fmaf_rn(q.x, wq1A[0], gA);
            gA = __fmaf_rn(q.y, wq1A[1], gA);
            gA = __fmaf_rn(q.z, wq1A[2], gA);
            gA = __fmaf_rn(q.w, wq1A[3], gA);
            float gB = c1B;
            gB = __fmaf_rn(q.x, wq1B[0], gB);
            gB = __fmaf_rn(q.y, wq1B[1], gB);
            gB = __fmaf_rn(q.z, wq1B[2], gB);
            gB = __fmaf_rn(q.w, wq1B[3], gB);
            _Float16 hA = (_Float16)gA, hB = (_Float16)gB;   // RN cvts
            unsigned pk = ((unsigned)__builtin_bit_cast(unsigned short, hB) << 16)
                        |  (unsigned)__builtin_bit_cast(unsigned short, hA);
            *reinterpret_cast<unsigned*>(&s_u.g16[r][2 * o2]) = pk;
        }
    }
    __syncthreads();

    // ---- Phase F: packed pairs, 2 rows per wave-iteration.  acc per lane
    //      covers channels (2*o2, 2*o2+1); halves process disjoint rows. ----
    float accA = -INF, accB = -INF;
    for (int t = wv * 2 + hlf; t < nv; t += 16) {
        const float4 q = *reinterpret_cast<const float4*>(&s_q[t][0]);
        float baseA = c2A;
        baseA = __fmaf_rn(q.x, wq2A[0], baseA);
        baseA = __fmaf_rn(q.y, wq2A[1], baseA);
        baseA = __fmaf_rn(q.z, wq2A[2], baseA);
        baseA = __fmaf_rn(q.w, wq2A[3], baseA);
        float baseB = c2B;
        baseB = __fmaf_rn(q.x, wq2B[0], baseB);
        baseB = __fmaf_rn(q.y, wq2B[1], baseB);
        baseB = __fmaf_rn(q.z, wq2B[2], baseB);
        baseB = __fmaf_rn(q.w, wq2B[3], baseB);
        uint2 pk = *reinterpret_cast<const uint2*>(&s_idxp[t][0]);  // broadcast
        int i0 =  pk.x        & 255, i1 = (pk.x >>  8) & 255;
        int i2_ = (pk.x >> 16) & 255, i3_ = (pk.x >> 24) & 255;
        int i4 =  pk.y        & 255, i5 = (pk.y >>  8) & 255;
        int i6 = (pk.y >> 16) & 255, i7 = (pk.y >> 24) & 255;
        // dword = fp16 channel pair; 7 pk_max = exact 8-way max per channel
        unsigned g0 = *reinterpret_cast<const unsigned*>(&s_u.g16[i0][2 * o2]);
        unsigned g1 = *reinterpret_cast<const unsigned*>(&s_u.g16[i1][2 * o2]);
        unsigned g2 = *reinterpret_cast<const unsigned*>(&s_u.g16[i2_][2 * o2]);
        unsigned g3 = *reinterpret_cast<const unsigned*>(&s_u.g16[i3_][2 * o2]);
        unsigned g4 = *reinterpret_cast<const unsigned*>(&s_u.g16[i4][2 * o2]);
        unsigned g5 = *reinterpret_cast<const unsigned*>(&s_u.g16[i5][2 * o2]);
        unsigned g6 = *reinterpret_cast<const unsigned*>(&s_u.g16[i6][2 * o2]);
        unsigned g7 = *reinterpret_cast<const unsigned*>(&s_u.g16[i7][2 * o2]);
        unsigned gm = pkmaxh(pkmaxh(pkmaxh(g0, g1), pkmaxh(g2, g3)),
                             pkmaxh(pkmaxh(g4, g5), pkmaxh(g6, g7)));
        float gA = (float)__builtin_bit_cast(_Float16, (unsigned short)(gm & 0xFFFFu));
        float gB = (float)__builtin_bit_cast(_Float16, (unsigned short)(gm >> 16));
        accA = fmaxf(accA, gA + baseA);    // fp32 epilogue: bit-identical to R10
        accB = fmaxf(accB, gB + baseB);
    }
    // combine halves (disjoint row sets, same channels), publish per wave
    accA = fmaxf(accA, __shfl_xor(accA, 32));
    accB = fmaxf(accB, __shfl_xor(accB, 32));
    if (hlf == 0) {
        s_red[wv][2 * o2]     = accA;
        s_red[wv][2 * o2 + 1] = accB;
    }
    __syncthreads();

    // ---- Phase G: cross-wave reduce, BN + leakyReLU + mask-max, store ----
    if (tid < CO) {
        float m = s_red[0][tid];
        #pragma unroll
        for (int i = 1; i < NW; ++i) m = fmaxf(m, s_red[i][tid]);
        float scale = bn_gamma[tid] / sqrtf(bn_var[tid] + 0.001f);
        float bias  = bn_beta[tid] - bn_mean[tid] * scale;
        float h = m * fabsf(scale) + bias;    // m tracks sgn*h_pre
        float a = (h > 0.f) ? h : 0.2f * h;   // leaky_relu
        if (nv < TPTS) a = fmaxf(a, 0.f);     // masked rows contribute 0
        out[v * CO + tid] = a;
    }
}

extern "C" void kernel_launch(void* const* d_in, const int* in_sizes, int n_in,
                              void* d_out, int out_size, void* d_ws, size_t ws_size,
                              hipStream_t stream) {
    const float* features = (const float*)d_in[0];
    const float* conv_w   = (const float*)d_in[1];
    const float* bn_gamma = (const float*)d_in[2];
    const float* bn_beta  = (const float*)d_in[3];
    const float* bn_mean  = (const float*)d_in[4];
    const float* bn_var   = (const float*)d_in[5];
    const int*   num_vox  = (const int*)d_in[6];
    const int*   coor     = (const int*)d_in[7];
    float* outp = (float*)d_out;
    const int V = in_sizes[6];   // 4096 voxels
    dgcnn_kernel<<<V, 512, 0, stream>>>(features, conv_w, bn_gamma, bn_beta,
                                        bn_mean, bn_var, num_vox, coor, outp);
}